// Round 1
// baseline (5996.448 us; speedup 1.0000x reference)
//
#include <hip/hip_runtime.h>
#include <math.h>

#define N_NODES 20000
#define N_EDGES 320000
#define HID 50
#define NC (2*HID)   // 100 output cols: [0,50)=message (Wm), [50,100)=edge update (We)

// ---------------------------------------------------------------------------
// Message + edge-update GEMM over edges.
// h[e] = concat(x[dst[e]] (F), x[src[e]] (F), ein[e] (FE))  -> K = 2F+FE
// out cols 0..49  : m = h@Wm + bm  -> atomicAdd into xo[dst]
// out cols 50..99 : e_new = h@We + be -> eout[e] (may alias ein, per-edge rows)
// Tile: ET edges per block; thread computes 4 edges x 4 cols.
// ---------------------------------------------------------------------------
template<int K, int F, int FE, int ET, int KC, int BLOCK, int HPAD>
__global__ __launch_bounds__(BLOCK) void msg_kernel(
    const float* __restrict__ xn,
    const float* __restrict__ ein,
    float* __restrict__ eout,
    const int* __restrict__ src_idx,
    const int* __restrict__ dst_idx,
    const float* __restrict__ Wm, const float* __restrict__ bm,
    const float* __restrict__ We, const float* __restrict__ be,
    float* __restrict__ xo)
{
    static_assert(K % KC == 0, "K divisible by KC");
    constexpr int NCHUNK = K / KC;
    constexpr int EG = ET / 4;        // edge groups of 4
    constexpr int NACT = EG * 25;     // active compute threads (25 col-groups of 4)

    __shared__ float Wl[KC][NC];
    __shared__ float hl[ET][K + HPAD];
    __shared__ int sdst[ET], ssrc[ET];

    const int t = threadIdx.x;
    const int ebase = blockIdx.x * ET;   // N_EDGES % ET == 0 for our configs

    if (t < ET) {
        sdst[t] = dst_idx[ebase + t];
        ssrc[t] = src_idx[ebase + t];
    }
    __syncthreads();

    // stage h tile (coalesced along k within each edge row)
    for (int idx = t; idx < ET * K; idx += BLOCK) {
        const int el = idx / K;
        const int k  = idx - el * K;
        float v;
        if (k < F)            v = xn[(size_t)sdst[el] * F + k];
        else if (k < 2 * F)   v = xn[(size_t)ssrc[el] * F + (k - F)];
        else                  v = ein[(size_t)(ebase + el) * FE + (k - 2 * F)];
        hl[el][k] = v;
    }

    const bool active = (t < NACT);
    const int eg = t / 25;
    const int cg = t - eg * 25;
    const int c0 = cg * 4;
    const int e0 = eg * 4;

    float acc[4][4];
    if (active) {
        #pragma unroll
        for (int j = 0; j < 4; ++j) {
            const int c = c0 + j;
            const float bj = (c < HID) ? bm[c] : be[c - HID];
            #pragma unroll
            for (int i = 0; i < 4; ++i) acc[i][j] = bj;
        }
    }

    for (int ch = 0; ch < NCHUNK; ++ch) {
        const int kb = ch * KC;
        __syncthreads();   // h staged / previous chunk's compute done
        for (int idx = t; idx < KC * NC; idx += BLOCK) {
            const int k = idx / NC;
            const int c = idx - k * NC;
            Wl[k][c] = (c < HID) ? Wm[(size_t)(kb + k) * HID + c]
                                 : We[(size_t)(kb + k) * HID + (c - HID)];
        }
        __syncthreads();
        if (active) {
            for (int k = 0; k < KC; ++k) {
                const float4 w = *(const float4*)&Wl[k][c0];
                const int kk = kb + k;
                const float h0 = hl[e0 + 0][kk];
                const float h1 = hl[e0 + 1][kk];
                const float h2 = hl[e0 + 2][kk];
                const float h3 = hl[e0 + 3][kk];
                acc[0][0] += h0 * w.x; acc[0][1] += h0 * w.y; acc[0][2] += h0 * w.z; acc[0][3] += h0 * w.w;
                acc[1][0] += h1 * w.x; acc[1][1] += h1 * w.y; acc[1][2] += h1 * w.z; acc[1][3] += h1 * w.w;
                acc[2][0] += h2 * w.x; acc[2][1] += h2 * w.y; acc[2][2] += h2 * w.z; acc[2][3] += h2 * w.w;
                acc[3][0] += h3 * w.x; acc[3][1] += h3 * w.y; acc[3][2] += h3 * w.z; acc[3][3] += h3 * w.w;
            }
        }
    }

    if (active) {
        #pragma unroll
        for (int i = 0; i < 4; ++i) {
            const int el = e0 + i;
            const int d = sdst[el];
            const size_t e = (size_t)(ebase + el);
            #pragma unroll
            for (int j = 0; j < 4; ++j) {
                const int c = c0 + j;
                const float v = acc[i][j];
                if (c < HID) atomicAdd(&xo[(size_t)d * HID + c], v);
                else         eout[e * HID + (c - HID)] = v;
            }
        }
    }
}

// one block per channel; mean + rstd over N_NODES rows
__global__ __launch_bounds__(1024) void stats_kernel(const float* __restrict__ v,
                                                     float* __restrict__ stats /* [2*HID] */)
{
    const int c = blockIdx.x;
    float s = 0.f, sq = 0.f;
    for (int r = threadIdx.x; r < N_NODES; r += 1024) {
        const float x = v[(size_t)r * HID + c];
        s += x; sq += x * x;
    }
    #pragma unroll
    for (int off = 32; off > 0; off >>= 1) {
        s  += __shfl_down(s, off);
        sq += __shfl_down(sq, off);
    }
    __shared__ float ls[16], lq[16];
    const int wid = threadIdx.x >> 6, lane = threadIdx.x & 63;
    if (lane == 0) { ls[wid] = s; lq[wid] = sq; }
    __syncthreads();
    if (threadIdx.x == 0) {
        s = 0.f; sq = 0.f;
        #pragma unroll
        for (int w = 0; w < 16; ++w) { s += ls[w]; sq += lq[w]; }
        const float mu = s / (float)N_NODES;
        const float var = sq / (float)N_NODES - mu * mu;
        stats[c] = mu;
        stats[HID + c] = rsqrtf(var + 1e-5f);
    }
}

// BN(train) + ELU + residual accumulate into cur
template<bool FIRST>
__global__ __launch_bounds__(256) void apply_kernel(const float* __restrict__ xo,
    const float* __restrict__ stats,
    const float* __restrict__ g, const float* __restrict__ b,
    float* __restrict__ cur)
{
    const int i = blockIdx.x * 256 + threadIdx.x;
    if (i >= N_NODES * HID) return;
    const int c = i % HID;
    const float z = (xo[i] - stats[c]) * stats[HID + c] * g[c] + b[c];
    const float a = (z > 0.f) ? z : expm1f(z);
    cur[i] = FIRST ? a : (cur[i] + a);
}

extern "C" void kernel_launch(void* const* d_in, const int* in_sizes, int n_in,
                              void* d_out, int out_size, void* d_ws, size_t ws_size,
                              hipStream_t stream)
{
    const float* x    = (const float*)d_in[0];               // [20000,64]
    const int*   ei   = (const int*)  d_in[1];               // [2,320000]
    const float* ea   = (const float*)d_in[2];               // [320000,112]
    // d_in[3] = distance — unused by reference
    const float* W1m  = (const float*)d_in[4];               // [240,50]
    const float* b1m  = (const float*)d_in[5];
    const float* W1e  = (const float*)d_in[6];
    const float* b1e  = (const float*)d_in[7];
    const float* g1   = (const float*)d_in[8];
    const float* bt1  = (const float*)d_in[9];
    const float* Wm   = (const float*)d_in[10];              // [9,150,50]
    const float* bm   = (const float*)d_in[11];              // [9,50]
    const float* We   = (const float*)d_in[12];
    const float* be   = (const float*)d_in[13];
    const float* gam  = (const float*)d_in[14];
    const float* bet  = (const float*)d_in[15];

    float* out = (float*)d_out;                              // cur: [20000,50]

    char* ws = (char*)d_ws;
    float* e_ws  = (float*)ws;                               // [320000,50] = 64 MB
    float* xo    = (float*)(ws + (size_t)64 * 1000 * 1000);  // [20000,50]  = 4 MB
    float* stats = (float*)(ws + (size_t)68 * 1000 * 1000);  // [100]

    const int* srcs = ei;            // edge_index[0]
    const int* dsts = ei + N_EDGES;  // edge_index[1]

    const int nApply = (N_NODES * HID + 255) / 256;

    // ---- layer 1: K=240 (F=64, FE=112), ET=32, KC=80, block=256, hpad=2 ----
    hipMemsetAsync(xo, 0, (size_t)N_NODES * HID * sizeof(float), stream);
    msg_kernel<240, 64, 112, 32, 80, 256, 2>
        <<<N_EDGES / 32, 256, 0, stream>>>(x, ea, e_ws, srcs, dsts,
                                           W1m, b1m, W1e, b1e, xo);
    stats_kernel<<<HID, 1024, 0, stream>>>(xo, stats);
    apply_kernel<true><<<nApply, 256, 0, stream>>>(xo, stats, g1, bt1, out);

    // ---- layers 2..10: K=150 (F=50, FE=50), ET=80, KC=30, block=512 ----
    for (int i = 0; i < 9; ++i) {
        hipMemsetAsync(xo, 0, (size_t)N_NODES * HID * sizeof(float), stream);
        msg_kernel<150, 50, 50, 80, 30, 512, 0>
            <<<N_EDGES / 80, 512, 0, stream>>>(out, e_ws, e_ws, srcs, dsts,
                                               Wm + (size_t)i * 150 * HID, bm + (size_t)i * HID,
                                               We + (size_t)i * 150 * HID, be + (size_t)i * HID,
                                               xo);
        stats_kernel<<<HID, 1024, 0, stream>>>(xo, stats);
        apply_kernel<false><<<nApply, 256, 0, stream>>>(xo, stats,
                                                        gam + (size_t)i * HID, bet + (size_t)i * HID,
                                                        out);
    }
}

// Round 2
// 2010.678 us; speedup vs baseline: 2.9823x; 2.9823x over previous
//
#include <hip/hip_runtime.h>
#include <hip/hip_bf16.h>
#include <math.h>

#define N_NODES 20000
#define N_EDGES 320000
#define HID 50

typedef short bf16x8 __attribute__((ext_vector_type(8)));
typedef float f32x4 __attribute__((ext_vector_type(4)));

__device__ inline ushort f2bf(float f) {
    __hip_bfloat16 h = __float2bfloat16(f);
    union { __hip_bfloat16 h; ushort u; } c; c.h = h; return c.u;
}
__device__ inline uint pack2(float a, float b) {
    return (uint)f2bf(a) | ((uint)f2bf(b) << 16);
}

// ---------------------------------------------------------------------------
// Build W^T bf16 [128][Kpad]: cols 0..49 = Wm, cols 64..113 = We, rest 0.
// bc[128] = fused bias vector. blockIdx.y = layer.
// ---------------------------------------------------------------------------
__global__ __launch_bounds__(256) void prep_w_kernel(
    const float* __restrict__ Wm, const float* __restrict__ We,
    const float* __restrict__ bm, const float* __restrict__ be,
    ushort* __restrict__ Wt, float* __restrict__ bc, int K, int Kpad)
{
    const int l = blockIdx.y;
    const float* Wm_l = Wm + (size_t)l * K * HID;
    const float* We_l = We + (size_t)l * K * HID;
    const float* bm_l = bm + (size_t)l * HID;
    const float* be_l = be + (size_t)l * HID;
    ushort* Wt_l = Wt + (size_t)l * 128 * Kpad;
    float*  bc_l = bc + (size_t)l * 128;
    for (int idx = blockIdx.x * 256 + threadIdx.x; idx < 128 * Kpad; idx += gridDim.x * 256) {
        const int c = idx / Kpad;
        const int k = idx - c * Kpad;
        float v = 0.f;
        if (k < K) {
            if (c < HID)                      v = Wm_l[(size_t)k * HID + c];
            else if (c >= 64 && c < 64 + HID) v = We_l[(size_t)k * HID + (c - 64)];
        }
        Wt_l[(size_t)c * Kpad + k] = f2bf(v);
        if (k == 0) {
            float b = 0.f;
            if (c < HID)                      b = bm_l[c];
            else if (c >= 64 && c < 64 + HID) b = be_l[c - 64];
            bc_l[c] = b;
        }
    }
}

// ---------------------------------------------------------------------------
// MFMA message+edge-update kernel.
// h[e] = [x[dst] (F) | x[src] (F) | e (FE)] -> bf16 in LDS, K padded to KPAD.
// C[64 edges][128 cols] = h @ Wt^T via mfma_f32_16x16x32_bf16.
// cols 0..49 -> atomicAdd xo[dst]; cols 64..113 -> eout (bf16, in-place ok).
// Block: 256 thr = 4 waves; wave w owns N-tiles {2w, 2w+1}; 4 M-tiles each.
// ---------------------------------------------------------------------------
template<int K, int F, int FE, int KPAD, int KPS, bool EBF16>
__global__ __launch_bounds__(256) void msg_mfma_kernel(
    const float* __restrict__ xn,
    const void*  __restrict__ ein_v,      // bf16 [E][FE] if EBF16 else fp32
    ushort* __restrict__ eout,            // bf16 [E][HID]
    const int* __restrict__ src_idx, const int* __restrict__ dst_idx,
    const ushort* __restrict__ Wt,        // bf16 [128][KPAD]
    const float* __restrict__ bc,         // [128]
    float* __restrict__ xo)
{
    constexpr int ET = 64, MT = 4, NCH = KPAD / 32, KP2 = KPAD / 2;
    __shared__ ushort hl[ET * KPS];
    __shared__ int sdst[ET], ssrc[ET];

    const int t = threadIdx.x;
    const int ebase = blockIdx.x * ET;

    if (t < ET) {
        sdst[t] = dst_idx[ebase + t];
        ssrc[t] = src_idx[ebase + t];
    }
    __syncthreads();

    // stage h tile as bf16 pairs (uint per thread-iter)
    for (int idx = t; idx < ET * KP2; idx += 256) {
        const int el = idx / KP2;
        const int k = (idx - el * KP2) * 2;
        uint w;
        if (k < F) {
            const float2 v = *(const float2*)&xn[(size_t)sdst[el] * F + k];
            w = pack2(v.x, v.y);
        } else if (k < 2 * F) {
            const float2 v = *(const float2*)&xn[(size_t)ssrc[el] * F + (k - F)];
            w = pack2(v.x, v.y);
        } else if (k < K) {
            if constexpr (EBF16) {
                w = *(const uint*)((const ushort*)ein_v + (size_t)(ebase + el) * FE + (k - 2 * F));
            } else {
                const float2 v = *(const float2*)((const float*)ein_v + (size_t)(ebase + el) * FE + (k - 2 * F));
                w = pack2(v.x, v.y);
            }
        } else {
            w = 0u;
        }
        *(uint*)&hl[el * KPS + k] = w;
    }
    __syncthreads();

    const int wid = t >> 6, lane = t & 63;
    const int cA = lane & 15, g = lane >> 4;

    bf16x8 Bfr[2][NCH];
    f32x4 acc[MT][2];
    #pragma unroll
    for (int tt = 0; tt < 2; ++tt) {
        const int col = (2 * wid + tt) * 16 + cA;
        const ushort* wrow = Wt + (size_t)col * KPAD + 8 * g;
        #pragma unroll
        for (int c = 0; c < NCH; ++c)
            Bfr[tt][c] = *(const bf16x8*)(wrow + c * 32);
        const float b = bc[col];
        #pragma unroll
        for (int m = 0; m < MT; ++m) acc[m][tt] = (f32x4){b, b, b, b};
    }

    #pragma unroll
    for (int c = 0; c < NCH; ++c) {
        bf16x8 afr[MT];
        #pragma unroll
        for (int m = 0; m < MT; ++m)
            afr[m] = *(const bf16x8*)&hl[(m * 16 + cA) * KPS + c * 32 + 8 * g];
        #pragma unroll
        for (int m = 0; m < MT; ++m) {
            acc[m][0] = __builtin_amdgcn_mfma_f32_16x16x32_bf16(afr[m], Bfr[0][c], acc[m][0], 0, 0, 0);
            acc[m][1] = __builtin_amdgcn_mfma_f32_16x16x32_bf16(afr[m], Bfr[1][c], acc[m][1], 0, 0, 0);
        }
    }

    // D layout: col = lane&15 (within tile), row = 4*(lane>>4)+r  [m89-verified]
    if (wid < 2) {
        #pragma unroll
        for (int tt = 0; tt < 2; ++tt) {
            const int col = (2 * wid + tt) * 16 + cA;
            if (col < HID) {
                #pragma unroll
                for (int m = 0; m < MT; ++m) {
                    #pragma unroll
                    for (int r = 0; r < 4; ++r) {
                        const int el = m * 16 + 4 * g + r;
                        atomicAdd(&xo[(size_t)sdst[el] * HID + col], acc[m][tt][r]);
                    }
                }
            }
        }
    } else {
        #pragma unroll
        for (int tt = 0; tt < 2; ++tt) {
            const int col = (2 * (wid - 2) + tt) * 16 + cA;   // tiles 4..7 -> e cols
            if (col < HID) {
                #pragma unroll
                for (int m = 0; m < MT; ++m) {
                    #pragma unroll
                    for (int r = 0; r < 4; ++r) {
                        const int el = m * 16 + 4 * g + r;
                        eout[(size_t)(ebase + el) * HID + col] = f2bf(acc[m][tt][r]);
                    }
                }
            }
        }
    }
}

// one block per channel; mean + rstd over N_NODES rows
__global__ __launch_bounds__(1024) void stats_kernel(const float* __restrict__ v,
                                                     float* __restrict__ stats)
{
    const int c = blockIdx.x;
    float s = 0.f, sq = 0.f;
    for (int r = threadIdx.x; r < N_NODES; r += 1024) {
        const float x = v[(size_t)r * HID + c];
        s += x; sq += x * x;
    }
    #pragma unroll
    for (int off = 32; off > 0; off >>= 1) {
        s  += __shfl_down(s, off);
        sq += __shfl_down(sq, off);
    }
    __shared__ float ls[16], lq[16];
    const int wid = threadIdx.x >> 6, lane = threadIdx.x & 63;
    if (lane == 0) { ls[wid] = s; lq[wid] = sq; }
    __syncthreads();
    if (threadIdx.x == 0) {
        s = 0.f; sq = 0.f;
        #pragma unroll
        for (int w = 0; w < 16; ++w) { s += ls[w]; sq += lq[w]; }
        const float mu = s / (float)N_NODES;
        const float var = sq / (float)N_NODES - mu * mu;
        stats[c] = mu;
        stats[HID + c] = rsqrtf(var + 1e-5f);
    }
}

template<bool FIRST>
__global__ __launch_bounds__(256) void apply_kernel(const float* __restrict__ xo,
    const float* __restrict__ stats,
    const float* __restrict__ g, const float* __restrict__ b,
    float* __restrict__ cur)
{
    const int i = blockIdx.x * 256 + threadIdx.x;
    if (i >= N_NODES * HID) return;
    const int c = i % HID;
    const float z = (xo[i] - stats[c]) * stats[HID + c] * g[c] + b[c];
    const float a = (z > 0.f) ? z : expm1f(z);
    cur[i] = FIRST ? a : (cur[i] + a);
}

extern "C" void kernel_launch(void* const* d_in, const int* in_sizes, int n_in,
                              void* d_out, int out_size, void* d_ws, size_t ws_size,
                              hipStream_t stream)
{
    const float* x    = (const float*)d_in[0];
    const int*   ei   = (const int*)  d_in[1];
    const float* ea   = (const float*)d_in[2];
    const float* W1m  = (const float*)d_in[4];
    const float* b1m  = (const float*)d_in[5];
    const float* W1e  = (const float*)d_in[6];
    const float* b1e  = (const float*)d_in[7];
    const float* g1   = (const float*)d_in[8];
    const float* bt1  = (const float*)d_in[9];
    const float* Wm   = (const float*)d_in[10];
    const float* bm   = (const float*)d_in[11];
    const float* We   = (const float*)d_in[12];
    const float* be   = (const float*)d_in[13];
    const float* gam  = (const float*)d_in[14];
    const float* bet  = (const float*)d_in[15];

    float* out = (float*)d_out;

    char* ws = (char*)d_ws;
    ushort* e_ws  = (ushort*)ws;                                 // [320000][50] bf16 = 32 MB
    float*  xo    = (float*)(ws + (size_t)32000000);             // [20000][50] fp32 = 4 MB
    float*  stats = (float*)(ws + (size_t)36000000);             // [100]
    ushort* Wt1   = (ushort*)(ws + (size_t)36000512);            // [128][256] bf16 = 64 KB
    float*  bc1   = (float*)(ws + (size_t)36066048);             // [128]
    ushort* Wtk   = (ushort*)(ws + (size_t)36066560);            // [9][128][160] bf16
    float*  bck   = (float*)(ws + (size_t)36435200);             // [9][128]

    const int* srcs = ei;
    const int* dsts = ei + N_EDGES;
    const int nApply = (N_NODES * HID + 255) / 256;

    prep_w_kernel<<<dim3(128, 1), 256, 0, stream>>>(W1m, W1e, b1m, b1e, Wt1, bc1, 240, 256);
    prep_w_kernel<<<dim3(128, 9), 256, 0, stream>>>(Wm, We, bm, be, Wtk, bck, 150, 160);

    // ---- layer 1: K=240 (F=64, FE=112 fp32), KPAD=256, KPS=264 ----
    hipMemsetAsync(xo, 0, (size_t)N_NODES * HID * sizeof(float), stream);
    msg_mfma_kernel<240, 64, 112, 256, 264, false>
        <<<N_EDGES / 64, 256, 0, stream>>>(x, ea, e_ws, srcs, dsts, Wt1, bc1, xo);
    stats_kernel<<<HID, 1024, 0, stream>>>(xo, stats);
    apply_kernel<true><<<nApply, 256, 0, stream>>>(xo, stats, g1, bt1, out);

    // ---- layers 2..10: K=150 (F=50, FE=50 bf16), KPAD=160, KPS=168 ----
    for (int i = 0; i < 9; ++i) {
        hipMemsetAsync(xo, 0, (size_t)N_NODES * HID * sizeof(float), stream);
        msg_mfma_kernel<150, 50, 50, 160, 168, true>
            <<<N_EDGES / 64, 256, 0, stream>>>(out, e_ws, e_ws, srcs, dsts,
                                               Wtk + (size_t)i * 128 * 160,
                                               bck + (size_t)i * 128, xo);
        stats_kernel<<<HID, 1024, 0, stream>>>(xo, stats);
        apply_kernel<false><<<nApply, 256, 0, stream>>>(xo, stats,
                                                        gam + (size_t)i * HID,
                                                        bet + (size_t)i * HID, out);
    }
}

// Round 4
// 979.566 us; speedup vs baseline: 6.1215x; 2.0526x over previous
//
#include <hip/hip_runtime.h>
#include <hip/hip_bf16.h>
#include <math.h>

#define N_NODES 20000
#define N_EDGES 320000
#define HID 50
#define XPAD 52   // padded row stride (ushorts) for bf16 node/edge state -> 104B, uint-aligned

typedef short bf16x8 __attribute__((ext_vector_type(8)));
typedef float f32x4 __attribute__((ext_vector_type(4)));

__device__ inline ushort f2bf(float f) {
    __hip_bfloat16 h = __float2bfloat16(f);
    union { __hip_bfloat16 h; ushort u; } c; c.h = h; return c.u;
}
__device__ inline uint pack2(float a, float b) {
    return (uint)f2bf(a) | ((uint)f2bf(b) << 16);
}

// ---------------------------------------------------------------------------
// Edge sorting by dst: histogram -> single-block scan -> atomic scatter.
// ---------------------------------------------------------------------------
__global__ __launch_bounds__(256) void hist_kernel(const int* __restrict__ dst, int* __restrict__ cnt) {
    const int e = blockIdx.x * 256 + threadIdx.x;
    if (e < N_EDGES) atomicAdd(&cnt[dst[e]], 1);
}

__global__ __launch_bounds__(1024) void scan_kernel(const int* __restrict__ cnt, int* __restrict__ offs) {
    __shared__ int part[1024];
    const int t = threadIdx.x;
    int loc[20]; int s = 0;
    #pragma unroll
    for (int i = 0; i < 20; ++i) {
        const int idx = t * 20 + i;
        const int v = (idx < N_NODES) ? cnt[idx] : 0;
        loc[i] = s; s += v;
    }
    part[t] = s; __syncthreads();
    for (int off = 1; off < 1024; off <<= 1) {
        const int v = (t >= off) ? part[t - off] : 0;
        __syncthreads();
        part[t] += v;
        __syncthreads();
    }
    const int ex = (t > 0) ? part[t - 1] : 0;
    #pragma unroll
    for (int i = 0; i < 20; ++i) {
        const int idx = t * 20 + i;
        if (idx < N_NODES) offs[idx] = ex + loc[i];
    }
}

__global__ __launch_bounds__(256) void scatter_kernel(const int* __restrict__ src, const int* __restrict__ dst,
        int* __restrict__ offs, int* __restrict__ perm,
        int* __restrict__ sdst_p, int* __restrict__ ssrc_p) {
    const int e = blockIdx.x * 256 + threadIdx.x;
    if (e >= N_EDGES) return;
    const int d = dst[e];
    const int pos = atomicAdd(&offs[d], 1);
    perm[pos] = e;
    sdst_p[pos] = d;
    ssrc_p[pos] = src[e];
}

__global__ __launch_bounds__(256) void xconv_kernel(const float* __restrict__ x, ushort* __restrict__ xb1) {
    const int i = blockIdx.x * 256 + threadIdx.x;
    if (i < N_NODES * 64) xb1[i] = f2bf(x[i]);
}

// ---------------------------------------------------------------------------
// Build W^T bf16 [128][Kpad]: cols 0..49 = Wm, cols 64..113 = We, rest 0.
// ---------------------------------------------------------------------------
__global__ __launch_bounds__(256) void prep_w_kernel(
    const float* __restrict__ Wm, const float* __restrict__ We,
    const float* __restrict__ bm, const float* __restrict__ be,
    ushort* __restrict__ Wt, float* __restrict__ bc, int K, int Kpad)
{
    const int l = blockIdx.y;
    const float* Wm_l = Wm + (size_t)l * K * HID;
    const float* We_l = We + (size_t)l * K * HID;
    const float* bm_l = bm + (size_t)l * HID;
    const float* be_l = be + (size_t)l * HID;
    ushort* Wt_l = Wt + (size_t)l * 128 * Kpad;
    float*  bc_l = bc + (size_t)l * 128;
    for (int idx = blockIdx.x * 256 + threadIdx.x; idx < 128 * Kpad; idx += gridDim.x * 256) {
        const int c = idx / Kpad;
        const int k = idx - c * Kpad;
        float v = 0.f;
        if (k < K) {
            if (c < HID)                      v = Wm_l[(size_t)k * HID + c];
            else if (c >= 64 && c < 64 + HID) v = We_l[(size_t)k * HID + (c - 64)];
        }
        Wt_l[(size_t)c * Kpad + k] = f2bf(v);
        if (k == 0) {
            float b = 0.f;
            if (c < HID)                      b = bm_l[c];
            else if (c >= 64 && c < 64 + HID) b = be_l[c - 64];
            bc_l[c] = b;
        }
    }
}

// ---------------------------------------------------------------------------
// MFMA message+edge-update kernel, dst-sorted edges, segmented scatter.
// h[e] = [x[dst] | x[src] | e] bf16 in LDS (K padded to KPAD).
// C[64][128] = h @ Wt^T; cols 0..49 -> segmented sum -> xo; 64..113 -> eout.
// ---------------------------------------------------------------------------
template<int K, int F, int FE, int KPAD, int KPS, int XS, bool L1>
__global__ __launch_bounds__(256) void msg_mfma_kernel(
    const ushort* __restrict__ xb,       // bf16 node features, row stride XS
    const float*  __restrict__ ea,       // L1: fp32 [E][FE] (original order)
    const ushort* __restrict__ ein,      // !L1: bf16 [E][XPAD] (sorted order)
    const int*    __restrict__ perm,     // L1: sorted -> original edge id
    ushort* __restrict__ eout,           // bf16 [E][XPAD] (sorted order)
    const int* __restrict__ sdst_idx, const int* __restrict__ ssrc_idx,  // sorted
    const ushort* __restrict__ Wt, const float* __restrict__ bc,
    float* __restrict__ xo)
{
    constexpr int ET = 64, MT = 4, NCH = KPAD / 32, KP2 = KPAD / 2;
    __shared__ __align__(16) ushort hl[ET * KPS];
    __shared__ int sdst[ET], ssrc[ET], sperm[ET];
    __shared__ int segStart[ET + 1];
    __shared__ int nseg_s;

    const int t = threadIdx.x;
    const int ebase = blockIdx.x * ET;

    if (t < ET) {
        sdst[t] = sdst_idx[ebase + t];
        ssrc[t] = ssrc_idx[ebase + t];
        if (L1) sperm[t] = perm[ebase + t];
    }
    __syncthreads();

    // stage h tile as bf16 pairs
    for (int idx = t; idx < ET * KP2; idx += 256) {
        const int el = idx / KP2;
        const int k = (idx - el * KP2) * 2;
        uint w;
        if (k < F)            w = *(const uint*)&xb[(size_t)sdst[el] * XS + k];
        else if (k < 2 * F)   w = *(const uint*)&xb[(size_t)ssrc[el] * XS + (k - F)];
        else if (k < K) {
            if constexpr (L1) {
                const float2 v = *(const float2*)&ea[(size_t)sperm[el] * FE + (k - 2 * F)];
                w = pack2(v.x, v.y);
            } else {
                w = *(const uint*)&ein[(size_t)(ebase + el) * XPAD + (k - 2 * F)];
            }
        } else w = 0u;
        *(uint*)&hl[el * KPS + k] = w;
    }
    __syncthreads();

    const int wid = t >> 6, lane = t & 63;
    const int cA = lane & 15, g = lane >> 4;

    bf16x8 Bfr[2][NCH];
    f32x4 acc[MT][2];
    #pragma unroll
    for (int tt = 0; tt < 2; ++tt) {
        const int col = (2 * wid + tt) * 16 + cA;
        const ushort* wrow = Wt + (size_t)col * KPAD + 8 * g;
        #pragma unroll
        for (int c = 0; c < NCH; ++c)
            Bfr[tt][c] = *(const bf16x8*)(wrow + c * 32);
        const float b = bc[col];
        #pragma unroll
        for (int m = 0; m < MT; ++m) acc[m][tt] = (f32x4){b, b, b, b};
    }

    #pragma unroll
    for (int c = 0; c < NCH; ++c) {
        bf16x8 afr[MT];
        #pragma unroll
        for (int m = 0; m < MT; ++m)
            afr[m] = *(const bf16x8*)&hl[(m * 16 + cA) * KPS + c * 32 + 8 * g];
        #pragma unroll
        for (int m = 0; m < MT; ++m) {
            acc[m][0] = __builtin_amdgcn_mfma_f32_16x16x32_bf16(afr[m], Bfr[0][c], acc[m][0], 0, 0, 0);
            acc[m][1] = __builtin_amdgcn_mfma_f32_16x16x32_bf16(afr[m], Bfr[1][c], acc[m][1], 0, 0, 0);
        }
    }

    __syncthreads();   // all hl reads done -> reuse as xol

    float* xol = (float*)hl;   // [64][XPAD] fp32 message tile

    // segment boundaries of sorted dst within the block (wave 0)
    if (wid == 0) {
        const int el = lane;
        const bool flag = (el == 0) || (sdst[el] != sdst[el - 1]);
        const unsigned long long mask = __ballot(flag);
        const int sid = __popcll(mask & ((1ull << el) - 1ull));
        if (flag) segStart[sid] = el;
        if (el == ET - 1) {
            const int ns = __popcll(mask);
            nseg_s = ns;
            segStart[ns] = ET;
        }
    }

    if (wid < 2) {
        // message half -> LDS for segmented reduction
        #pragma unroll
        for (int tt = 0; tt < 2; ++tt) {
            const int col = (2 * wid + tt) * 16 + cA;
            if (col < HID) {
                #pragma unroll
                for (int m = 0; m < MT; ++m) {
                    #pragma unroll
                    for (int r = 0; r < 4; ++r)
                        xol[(m * 16 + 4 * g + r) * XPAD + col] = acc[m][tt][r];
                }
            }
        }
    } else {
        // edge-update half -> global (in-place rows are this block's own)
        #pragma unroll
        for (int tt = 0; tt < 2; ++tt) {
            const int col = (2 * (wid - 2) + tt) * 16 + cA;
            if (col < HID) {
                #pragma unroll
                for (int m = 0; m < MT; ++m) {
                    #pragma unroll
                    for (int r = 0; r < 4; ++r) {
                        const int el = m * 16 + 4 * g + r;
                        eout[(size_t)(ebase + el) * XPAD + col] = f2bf(acc[m][tt][r]);
                    }
                }
            }
        }
    }
    __syncthreads();

    // segmented sum: one atomicAdd per (segment, col).
    // (all-atomic: avoids mixing plain stores + remote atomics in one cache line)
    const int nseg = nseg_s;
    for (int idx = t; idx < nseg * HID; idx += 256) {
        const int s = idx / HID;
        const int col = idx - s * HID;
        const int a0 = segStart[s], b0 = segStart[s + 1];
        float sum = 0.f;
        for (int r = a0; r < b0; ++r) sum += xol[r * XPAD + col];
        atomicAdd(&xo[(size_t)sdst[a0] * HID + col], sum);
    }
}

// coalesced column stats: 80 blocks, each covers a contiguous 12500-elem span
// with 250 threads x 50 iters (stride 250); partials -> atomics into sacc[100]
__global__ __launch_bounds__(256) void stats_kernel(const float* __restrict__ xo,
                                                    float* __restrict__ sacc)
{
    __shared__ float sp[5][HID], sq[5][HID];
    const int t = threadIdx.x;
    if (t < 250) {
        float s = 0.f, q = 0.f;
        const size_t base = (size_t)blockIdx.x * 12500 + t;
        #pragma unroll
        for (int it = 0; it < 50; ++it) {
            const float v = xo[base + it * 250];
            s += v; q += v * v;
        }
        sp[t / HID][t % HID] = s;
        sq[t / HID][t % HID] = q;
    }
    __syncthreads();
    if (t < HID) {
        float s = 0.f, q = 0.f;
        #pragma unroll
        for (int p = 0; p < 5; ++p) { s += sp[p][t]; q += sq[p][t]; }
        atomicAdd(&sacc[t], s);
        atomicAdd(&sacc[HID + t], q);
    }
}

// BN(train) + ELU + residual; also maintains bf16 mirror xb of cur
template<bool FIRST>
__global__ __launch_bounds__(256) void apply_kernel(const float* __restrict__ xo,
    const float* __restrict__ sacc,
    const float* __restrict__ g, const float* __restrict__ b,
    float* __restrict__ cur, ushort* __restrict__ xb)
{
    const int i = blockIdx.x * 256 + threadIdx.x;
    if (i >= N_NODES * HID) return;
    const int c = i % HID;
    const float inv = 1.f / (float)N_NODES;
    const float mu = sacc[c] * inv;
    const float var = sacc[HID + c] * inv - mu * mu;
    const float z = (xo[i] - mu) * rsqrtf(var + 1e-5f) * g[c] + b[c];
    const float a = (z > 0.f) ? z : expm1f(z);
    const float nc = FIRST ? a : (cur[i] + a);
    cur[i] = nc;
    xb[(size_t)(i / HID) * XPAD + c] = f2bf(nc);
}

extern "C" void kernel_launch(void* const* d_in, const int* in_sizes, int n_in,
                              void* d_out, int out_size, void* d_ws, size_t ws_size,
                              hipStream_t stream)
{
    const float* x    = (const float*)d_in[0];
    const int*   ei   = (const int*)  d_in[1];
    const float* ea   = (const float*)d_in[2];
    const float* W1m  = (const float*)d_in[4];
    const float* b1m  = (const float*)d_in[5];
    const float* W1e  = (const float*)d_in[6];
    const float* b1e  = (const float*)d_in[7];
    const float* g1   = (const float*)d_in[8];
    const float* bt1  = (const float*)d_in[9];
    const float* Wm   = (const float*)d_in[10];
    const float* bm   = (const float*)d_in[11];
    const float* We   = (const float*)d_in[12];
    const float* be   = (const float*)d_in[13];
    const float* gam  = (const float*)d_in[14];
    const float* bet  = (const float*)d_in[15];

    float* out = (float*)d_out;

    char* ws = (char*)d_ws;
    ushort* e_ws   = (ushort*)(ws + 0);                      // [E][52] bf16   33,280,000
    float*  xo     = (float*) (ws + 33280000);               // [20000][50]     4,000,000
    float*  sacc   = (float*) (ws + 37280000);               // [100] + pad           512
    ushort* Wt1    = (ushort*)(ws + 37280512);               // [128][256]         65,536
    float*  bc1    = (float*) (ws + 37346048);               // [128]                 512
    ushort* Wtk    = (ushort*)(ws + 37346560);               // [9][128][160]     368,640
    float*  bck    = (float*) (ws + 37715200);               // [9][128] + pad      5,120
    ushort* xb1    = (ushort*)(ws + 37720320);               // [20000][64]     2,560,000
    ushort* xb     = (ushort*)(ws + 40280320);               // [20000][52]     2,080,000
    int*    cnt    = (int*)   (ws + 42360320);               // [20000]            80,000
    int*    offs   = (int*)   (ws + 42440320);               // [20000]            80,000
    int*    perm   = (int*)   (ws + 42520320);               // [E]             1,280,000
    int*    sdst_p = (int*)   (ws + 43800320);               // [E]             1,280,000
    int*    ssrc_p = (int*)   (ws + 45080320);               // [E]             1,280,000

    const int* srcs = ei;
    const int* dsts = ei + N_EDGES;
    const int nApply = (N_NODES * HID + 255) / 256;

    // ---- one-time prep: sort edges by dst, convert x, transpose weights ----
    hipMemsetAsync(cnt, 0, N_NODES * sizeof(int), stream);
    hist_kernel<<<1250, 256, 0, stream>>>(dsts, cnt);
    scan_kernel<<<1, 1024, 0, stream>>>(cnt, offs);
    scatter_kernel<<<1250, 256, 0, stream>>>(srcs, dsts, offs, perm, sdst_p, ssrc_p);
    xconv_kernel<<<5000, 256, 0, stream>>>(x, xb1);
    prep_w_kernel<<<dim3(128, 1), 256, 0, stream>>>(W1m, W1e, b1m, b1e, Wt1, bc1, 240, 256);
    prep_w_kernel<<<dim3(128, 9), 256, 0, stream>>>(Wm, We, bm, be, Wtk, bck, 150, 160);

    // ---- layer 1: K=240 (F=64 bf16, FE=112 fp32 via perm) ----
    hipMemsetAsync(xo, 0, 4000512, stream);   // xo + sacc
    msg_mfma_kernel<240, 64, 112, 256, 264, 64, true>
        <<<N_EDGES / 64, 256, 0, stream>>>(xb1, ea, (const ushort*)nullptr, perm,
                                           e_ws, sdst_p, ssrc_p, Wt1, bc1, xo);
    stats_kernel<<<80, 256, 0, stream>>>(xo, sacc);
    apply_kernel<true><<<nApply, 256, 0, stream>>>(xo, sacc, g1, bt1, out, xb);

    // ---- layers 2..10: K=150 (F=50 bf16, FE=50 bf16 in-place) ----
    for (int i = 0; i < 9; ++i) {
        hipMemsetAsync(xo, 0, 4000512, stream);
        msg_mfma_kernel<150, 50, 50, 160, 168, XPAD, false>
            <<<N_EDGES / 64, 256, 0, stream>>>(xb, (const float*)nullptr, e_ws, (const int*)nullptr,
                                               e_ws, sdst_p, ssrc_p,
                                               Wtk + (size_t)i * 128 * 160,
                                               bck + (size_t)i * 128, xo);
        stats_kernel<<<80, 256, 0, stream>>>(xo, sacc);
        apply_kernel<false><<<nApply, 256, 0, stream>>>(xo, sacc,
                                                        gam + (size_t)i * HID,
                                                        bet + (size_t)i * HID, out, xb);
    }
}

// Round 5
// 718.369 us; speedup vs baseline: 8.3473x; 1.3636x over previous
//
#include <hip/hip_runtime.h>
#include <hip/hip_bf16.h>
#include <math.h>

#define N_NODES 20000
#define N_EDGES 320000
#define HID 50
#define XS 64     // row stride (ushorts) for all bf16 node/edge state -> 128 B, 16B-aligned

typedef short bf16x8 __attribute__((ext_vector_type(8)));
typedef float f32x4 __attribute__((ext_vector_type(4)));

__device__ inline ushort f2bf(float f) {
    __hip_bfloat16 h = __float2bfloat16(f);
    union { __hip_bfloat16 h; ushort u; } c; c.h = h; return c.u;
}
__device__ inline uint pack2(float a, float b) {
    return (uint)f2bf(a) | ((uint)f2bf(b) << 16);
}

// ---------------------------------------------------------------------------
// Edge sorting by dst: histogram -> single-block scan -> atomic scatter.
// ---------------------------------------------------------------------------
__global__ __launch_bounds__(256) void hist_kernel(const int* __restrict__ dst, int* __restrict__ cnt) {
    const int e = blockIdx.x * 256 + threadIdx.x;
    if (e < N_EDGES) atomicAdd(&cnt[dst[e]], 1);
}

__global__ __launch_bounds__(1024) void scan_kernel(const int* __restrict__ cnt, int* __restrict__ offs) {
    __shared__ int part[1024];
    const int t = threadIdx.x;
    int loc[20]; int s = 0;
    #pragma unroll
    for (int i = 0; i < 20; ++i) {
        const int idx = t * 20 + i;
        const int v = (idx < N_NODES) ? cnt[idx] : 0;
        loc[i] = s; s += v;
    }
    part[t] = s; __syncthreads();
    for (int off = 1; off < 1024; off <<= 1) {
        const int v = (t >= off) ? part[t - off] : 0;
        __syncthreads();
        part[t] += v;
        __syncthreads();
    }
    const int ex = (t > 0) ? part[t - 1] : 0;
    #pragma unroll
    for (int i = 0; i < 20; ++i) {
        const int idx = t * 20 + i;
        if (idx < N_NODES) offs[idx] = ex + loc[i];
    }
}

__global__ __launch_bounds__(256) void scatter_kernel(const int* __restrict__ src, const int* __restrict__ dst,
        int* __restrict__ offs, int* __restrict__ perm,
        int* __restrict__ sdst_p, int* __restrict__ ssrc_p) {
    const int e = blockIdx.x * 256 + threadIdx.x;
    if (e >= N_EDGES) return;
    const int d = dst[e];
    const int pos = atomicAdd(&offs[d], 1);
    perm[pos] = e;
    sdst_p[pos] = d;
    ssrc_p[pos] = src[e];
}

__global__ __launch_bounds__(256) void xconv_kernel(const float* __restrict__ x, ushort* __restrict__ xb1) {
    const int i = blockIdx.x * 256 + threadIdx.x;
    if (i < N_NODES * 64) xb1[i] = f2bf(x[i]);   // XS==64 == feature count: dense
}

// ---------------------------------------------------------------------------
// Build W^T bf16 [128][Kpad], section layout: orig W rows [0,F) -> k 0..,
// [F,2F) -> k 64.., [2F,2F+FE) -> k 128..; other k rows are ZERO.
// cols 0..49 = Wm, cols 64..113 = We, rest 0. bc[128] = fused bias.
// ---------------------------------------------------------------------------
__global__ __launch_bounds__(256) void prep_w_kernel(
    const float* __restrict__ Wm, const float* __restrict__ We,
    const float* __restrict__ bm, const float* __restrict__ be,
    ushort* __restrict__ Wt, float* __restrict__ bc, int F, int FE, int Kpad)
{
    const int l = blockIdx.y;
    const int K = 2 * F + FE;
    const float* Wm_l = Wm + (size_t)l * K * HID;
    const float* We_l = We + (size_t)l * K * HID;
    const float* bm_l = bm + (size_t)l * HID;
    const float* be_l = be + (size_t)l * HID;
    ushort* Wt_l = Wt + (size_t)l * 128 * Kpad;
    float*  bc_l = bc + (size_t)l * 128;
    for (int idx = blockIdx.x * 256 + threadIdx.x; idx < 128 * Kpad; idx += gridDim.x * 256) {
        const int c = idx / Kpad;
        const int k = idx - c * Kpad;
        int r = -1;
        if (k < 64)       { if (k < F)        r = k; }
        else if (k < 128) { if (k - 64 < F)   r = F + (k - 64); }
        else              { if (k - 128 < FE) r = 2 * F + (k - 128); }
        float v = 0.f;
        if (r >= 0) {
            if (c < HID)                      v = Wm_l[(size_t)r * HID + c];
            else if (c >= 64 && c < 64 + HID) v = We_l[(size_t)r * HID + (c - 64)];
        }
        Wt_l[(size_t)c * Kpad + k] = f2bf(v);
        if (k == 0) {
            float b = 0.f;
            if (c < HID)                      b = bm_l[c];
            else if (c >= 64 && c < 64 + HID) b = be_l[c - 64];
            bc_l[c] = b;
        }
    }
}

// ---------------------------------------------------------------------------
// MFMA message+edge-update kernel, dst-sorted edges, segmented scatter.
// h sections: dst [0,64), src [64,128), e [128,..); 16B-vectorized staging.
// C[64][128] = h @ Wt^T; cols 0..49 -> segmented sum -> xo; 64..113 -> eout.
// ---------------------------------------------------------------------------
template<int FE, int KPAD, int KPS, bool L1>
__global__ __launch_bounds__(256) void msg_mfma_kernel(
    const ushort* __restrict__ xb,       // bf16 node features, row stride XS
    const float*  __restrict__ ea,       // L1: fp32 [E][FE] (original order)
    const ushort* __restrict__ ein,      // !L1: bf16 [E][XS] (sorted order)
    const int*    __restrict__ perm,     // L1: sorted -> original edge id
    ushort* __restrict__ eout,           // bf16 [E][XS] (sorted order)
    const int* __restrict__ sdst_idx, const int* __restrict__ ssrc_idx,  // sorted
    const ushort* __restrict__ Wt, const float* __restrict__ bc,
    float* __restrict__ xo)
{
    constexpr int ET = 64, MT = 4, NCH = KPAD / 32;
    __shared__ __align__(16) ushort hl[ET * KPS];
    __shared__ int sdst[ET], ssrc[ET], sperm[ET];
    __shared__ int segStart[ET + 1];
    __shared__ int nseg_s;

    const int t = threadIdx.x;
    const int ebase = blockIdx.x * ET;

    if (t < ET) {
        sdst[t] = sdst_idx[ebase + t];
        ssrc[t] = ssrc_idx[ebase + t];
        if (L1) sperm[t] = perm[ebase + t];
    }
    __syncthreads();

    // ---- staging: three branch-free 16B-vector loops ----
    for (int idx = t; idx < ET * 8; idx += 256) {            // dst rows -> [0,64)
        const int el = idx >> 3, ch = idx & 7;
        const int4 v = *(const int4*)(xb + (size_t)sdst[el] * XS + ch * 8);
        *(int4*)&hl[el * KPS + ch * 8] = v;
    }
    for (int idx = t; idx < ET * 8; idx += 256) {            // src rows -> [64,128)
        const int el = idx >> 3, ch = idx & 7;
        const int4 v = *(const int4*)(xb + (size_t)ssrc[el] * XS + ch * 8);
        *(int4*)&hl[el * KPS + 64 + ch * 8] = v;
    }
    if constexpr (L1) {
        for (int idx = t; idx < ET * 14; idx += 256) {       // ea fp32 -> bf16 [128,240)
            const int el = idx / 14, ch = idx - el * 14;
            const float* p = ea + (size_t)sperm[el] * FE + ch * 8;
            const float4 a = *(const float4*)p;
            const float4 b = *(const float4*)(p + 4);
            int4 w;
            w.x = (int)pack2(a.x, a.y); w.y = (int)pack2(a.z, a.w);
            w.z = (int)pack2(b.x, b.y); w.w = (int)pack2(b.z, b.w);
            *(int4*)&hl[el * KPS + 128 + ch * 8] = w;
        }
        for (int idx = t; idx < ET * 2; idx += 256) {        // zero tail [240,256)
            const int el = idx >> 1, ch = idx & 1;
            *(int4*)&hl[el * KPS + 240 + ch * 8] = (int4){0, 0, 0, 0};
        }
    } else {
        for (int idx = t; idx < ET * 8; idx += 256) {        // e rows -> [128,192)
            const int el = idx >> 3, ch = idx & 7;
            const int4 v = *(const int4*)(ein + (size_t)(ebase + el) * XS + ch * 8);
            *(int4*)&hl[el * KPS + 128 + ch * 8] = v;
        }
    }
    __syncthreads();

    const int wid = t >> 6, lane = t & 63;
    const int cA = lane & 15, g = lane >> 4;

    bf16x8 Bfr[2][NCH];
    f32x4 acc[MT][2];
    #pragma unroll
    for (int tt = 0; tt < 2; ++tt) {
        const int col = (2 * wid + tt) * 16 + cA;
        const ushort* wrow = Wt + (size_t)col * KPAD + 8 * g;
        #pragma unroll
        for (int c = 0; c < NCH; ++c)
            Bfr[tt][c] = *(const bf16x8*)(wrow + c * 32);
        const float b = bc[col];
        #pragma unroll
        for (int m = 0; m < MT; ++m) acc[m][tt] = (f32x4){b, b, b, b};
    }

    #pragma unroll
    for (int c = 0; c < NCH; ++c) {
        bf16x8 afr[MT];
        #pragma unroll
        for (int m = 0; m < MT; ++m)
            afr[m] = *(const bf16x8*)&hl[(m * 16 + cA) * KPS + c * 32 + 8 * g];
        #pragma unroll
        for (int m = 0; m < MT; ++m) {
            acc[m][0] = __builtin_amdgcn_mfma_f32_16x16x32_bf16(afr[m], Bfr[0][c], acc[m][0], 0, 0, 0);
            acc[m][1] = __builtin_amdgcn_mfma_f32_16x16x32_bf16(afr[m], Bfr[1][c], acc[m][1], 0, 0, 0);
        }
    }

    __syncthreads();   // all hl reads done -> reuse as xol

    float* xol = (float*)hl;   // [64][52] fp32 message tile

    // segment boundaries of sorted dst within the block (wave 0)
    if (wid == 0) {
        const int el = lane;
        const bool flag = (el == 0) || (sdst[el] != sdst[el - 1]);
        const unsigned long long mask = __ballot(flag);
        const int sid = __popcll(mask & ((1ull << el) - 1ull));
        if (flag) segStart[sid] = el;
        if (el == ET - 1) {
            const int ns = __popcll(mask);
            nseg_s = ns;
            segStart[ns] = ET;
        }
    }

    if (wid < 2) {
        // message half -> LDS for segmented reduction
        #pragma unroll
        for (int tt = 0; tt < 2; ++tt) {
            const int col = (2 * wid + tt) * 16 + cA;
            if (col < HID) {
                #pragma unroll
                for (int m = 0; m < MT; ++m) {
                    #pragma unroll
                    for (int r = 0; r < 4; ++r)
                        xol[(m * 16 + 4 * g + r) * 52 + col] = acc[m][tt][r];
                }
            }
        }
    } else {
        // edge-update half -> global (in-place rows are this block's own)
        #pragma unroll
        for (int tt = 0; tt < 2; ++tt) {
            const int col = (2 * (wid - 2) + tt) * 16 + cA;
            if (col < HID) {
                #pragma unroll
                for (int m = 0; m < MT; ++m) {
                    #pragma unroll
                    for (int r = 0; r < 4; ++r) {
                        const int el = m * 16 + 4 * g + r;
                        eout[(size_t)(ebase + el) * XS + col] = f2bf(acc[m][tt][r]);
                    }
                }
            }
        }
    }
    __syncthreads();

    // segmented sum: one atomicAdd per (segment, col)
    const int nseg = nseg_s;
    for (int idx = t; idx < nseg * HID; idx += 256) {
        const int s = idx / HID;
        const int col = idx - s * HID;
        const int a0 = segStart[s], b0 = segStart[s + 1];
        float sum = 0.f;
        for (int r = a0; r < b0; ++r) sum += xol[r * 52 + col];
        atomicAdd(&xo[(size_t)sdst[a0] * HID + col], sum);
    }
}

// coalesced column stats: 80 blocks, contiguous 12500-elem span each,
// 250 threads x 50 iters (stride 250); partials -> atomics into sacc slot
__global__ __launch_bounds__(256) void stats_kernel(const float* __restrict__ xo,
                                                    float* __restrict__ sacc)
{
    __shared__ float sp[5][HID], sq[5][HID];
    const int t = threadIdx.x;
    if (t < 250) {
        float s = 0.f, q = 0.f;
        const size_t base = (size_t)blockIdx.x * 12500 + t;
        #pragma unroll
        for (int it = 0; it < 50; ++it) {
            const float v = xo[base + it * 250];
            s += v; q += v * v;
        }
        sp[t / HID][t % HID] = s;
        sq[t / HID][t % HID] = q;
    }
    __syncthreads();
    if (t < HID) {
        float s = 0.f, q = 0.f;
        #pragma unroll
        for (int p = 0; p < 5; ++p) { s += sp[p][t]; q += sq[p][t]; }
        atomicAdd(&sacc[t], s);
        atomicAdd(&sacc[HID + t], q);
    }
}

// BN(train) + ELU + residual; maintains bf16 mirror xb; zeroes xo for next layer
template<bool FIRST>
__global__ __launch_bounds__(256) void apply_kernel(float* __restrict__ xo,
    const float* __restrict__ sacc,
    const float* __restrict__ g, const float* __restrict__ b,
    float* __restrict__ cur, ushort* __restrict__ xb)
{
    const int i = blockIdx.x * 256 + threadIdx.x;
    if (i >= N_NODES * HID) return;
    const int c = i % HID;
    const float inv = 1.f / (float)N_NODES;
    const float mu = sacc[c] * inv;
    const float var = sacc[HID + c] * inv - mu * mu;
    const float z = (xo[i] - mu) * rsqrtf(var + 1e-5f) * g[c] + b[c];
    xo[i] = 0.f;                               // ready for next layer's atomics
    const float a = (z > 0.f) ? z : expm1f(z);
    const float nc = FIRST ? a : (cur[i] + a);
    cur[i] = nc;
    xb[(size_t)(i / HID) * XS + c] = f2bf(nc);
}

extern "C" void kernel_launch(void* const* d_in, const int* in_sizes, int n_in,
                              void* d_out, int out_size, void* d_ws, size_t ws_size,
                              hipStream_t stream)
{
    const float* x    = (const float*)d_in[0];
    const int*   ei   = (const int*)  d_in[1];
    const float* ea   = (const float*)d_in[2];
    const float* W1m  = (const float*)d_in[4];
    const float* b1m  = (const float*)d_in[5];
    const float* W1e  = (const float*)d_in[6];
    const float* b1e  = (const float*)d_in[7];
    const float* g1   = (const float*)d_in[8];
    const float* bt1  = (const float*)d_in[9];
    const float* Wm   = (const float*)d_in[10];
    const float* bm   = (const float*)d_in[11];
    const float* We   = (const float*)d_in[12];
    const float* be   = (const float*)d_in[13];
    const float* gam  = (const float*)d_in[14];
    const float* bet  = (const float*)d_in[15];

    float* out = (float*)d_out;

    char* ws = (char*)d_ws;
    ushort* e_ws   = (ushort*)(ws + 0);                      // [E][64] bf16   40,960,000
    float*  xo     = (float*) (ws + 40960000);               // [20000][50]     4,000,000
    float*  sacc   = (float*) (ws + 44960000);               // [10][128]           5,120
    ushort* Wt1    = (ushort*)(ws + 44965120);               // [128][256]         65,536
    float*  bc1    = (float*) (ws + 45030656);               // [128]                 512
    ushort* Wtk    = (ushort*)(ws + 45031168);               // [9][128][192]     442,368
    float*  bck    = (float*) (ws + 45473536);               // [9][128] + pad      5,120
    ushort* xb1    = (ushort*)(ws + 45478656);               // [20000][64]     2,560,000
    ushort* xb     = (ushort*)(ws + 48038656);               // [20000][64]     2,560,000
    int*    cnt    = (int*)   (ws + 50598656);               // [20000]            80,000
    int*    offs   = (int*)   (ws + 50678656);               // [20000]            80,000
    int*    perm   = (int*)   (ws + 50758656);               // [E]             1,280,000
    int*    sdst_p = (int*)   (ws + 52038656);               // [E]             1,280,000
    int*    ssrc_p = (int*)   (ws + 53318656);               // [E]             1,280,000

    const int* srcs = ei;
    const int* dsts = ei + N_EDGES;
    const int nApply = (N_NODES * HID + 255) / 256;

    // ---- one-time prep: sanitize state, sort edges by dst, convert, transpose ----
    hipMemsetAsync(e_ws, 0, 44965120, stream);               // e_ws + xo + sacc
    hipMemsetAsync(xb, 0, 2560000, stream);                  // pad cols of xb
    hipMemsetAsync(cnt, 0, N_NODES * sizeof(int), stream);
    hist_kernel<<<1250, 256, 0, stream>>>(dsts, cnt);
    scan_kernel<<<1, 1024, 0, stream>>>(cnt, offs);
    scatter_kernel<<<1250, 256, 0, stream>>>(srcs, dsts, offs, perm, sdst_p, ssrc_p);
    xconv_kernel<<<5000, 256, 0, stream>>>(x, xb1);
    prep_w_kernel<<<dim3(128, 1), 256, 0, stream>>>(W1m, W1e, b1m, b1e, Wt1, bc1, 64, 112, 256);
    prep_w_kernel<<<dim3(128, 9), 256, 0, stream>>>(Wm, We, bm, be, Wtk, bck, 50, 50, 192);

    // ---- layer 1: F=64 bf16, FE=112 fp32 via perm; KPAD=256 ----
    msg_mfma_kernel<112, 256, 264, true>
        <<<N_EDGES / 64, 256, 0, stream>>>(xb1, ea, (const ushort*)nullptr, perm,
                                           e_ws, sdst_p, ssrc_p, Wt1, bc1, xo);
    stats_kernel<<<80, 256, 0, stream>>>(xo, sacc);
    apply_kernel<true><<<nApply, 256, 0, stream>>>(xo, sacc, g1, bt1, out, xb);

    // ---- layers 2..10: F=50, FE=50 bf16 in-place; KPAD=192 ----
    for (int i = 0; i < 9; ++i) {
        msg_mfma_kernel<50, 192, 200, false>
            <<<N_EDGES / 64, 256, 0, stream>>>(xb, (const float*)nullptr, e_ws, (const int*)nullptr,
                                               e_ws, sdst_p, ssrc_p,
                                               Wtk + (size_t)i * 128 * 192,
                                               bck + (size_t)i * 128, xo);
        stats_kernel<<<80, 256, 0, stream>>>(xo, sacc + (i + 1) * 128);
        apply_kernel<false><<<nApply, 256, 0, stream>>>(xo, sacc + (i + 1) * 128,
                                                        gam + (size_t)i * HID,
                                                        bet + (size_t)i * HID, out, xb);
    }
}